// Round 7
// baseline (63.865 us; speedup 1.0000x reference)
//
#include <hip/hip_runtime.h>
#include <hip/hip_bf16.h>

#define NN    4096      // nodes
#define DD    256       // feature dim (= H*HID)
#define NH    4         // heads
#define HIDD  64        // per-head hidden
#define NE    131072    // edges
#define WPR   (NN/32)   // 128 u32 words per adjacency bitmask row
#define SLOPE 0.2f
#define CAP   128       // max degree; Binom(131072,1/4096) max over 4096 rows ~56 incl self

// ---------------------------------------------------------------- K1: zero(adj) + self-loops + Wh(bf16) = X@W + e1/e2
// 256 blocks. Block b owns rows [16b,16b+16) and their adjacency words.
// NO LDS in the GEMM (R6 lesson: per-FMA ds_read broadcasts saturate the
// CU LDS pipe at ~5.8cyc/read -> 40us). Register outer product instead:
// wave(wr,wc) = rows [8wr,8wr+8) x cols [128wc,128wc+128); thread = 8 rows
// x 2 cols {lane, lane+64} == one col in head 2wc and one in head 2wc+1.
// `in` loads are lane-uniform float4 (scalarizable, off the LDS pipe);
// 16 FMAs amortize each x-load. e1/e2 dots: full-wave shuffle reductions.
__global__ __launch_bounds__(256) void k1_gemm_e12_zero(
    const float* __restrict__ in, const float* __restrict__ W,
    const float* __restrict__ att, __hip_bfloat16* __restrict__ Whb,
    float* __restrict__ e1, float* __restrict__ e2,
    unsigned int* __restrict__ adj) {
    int b    = blockIdx.x;
    int t    = threadIdx.x;
    int lane = t & 63, wv = t >> 6;
    int wr   = wv >> 1, wc = wv & 1;
    int row0 = b * 16 + wr * 8;
    int h0   = 2 * wc, h1 = h0 + 1;
    int c0   = h0 * HIDD + lane;           // col in head h0
    int c1   = c0 + 64;                    // col in head h1

    // zero adj slice: block b owns uint4 [512b,512b+512) == rows [16b,16b+16)
    uint4* adj4 = (uint4*)adj;
    uint4  z{0u, 0u, 0u, 0u};
    adj4[b * 512 + t]       = z;
    adj4[b * 512 + 256 + t] = z;
    __syncthreads();                       // zeros visible before self-bit stores
    if (t < 16) {                          // self-loop bit, within own zero slice
        int i = b * 16 + t;
        adj[i * WPR + (i >> 5)] = 1u << (i & 31);
    }

    float acc0[8], acc1[8];
    #pragma unroll
    for (int r = 0; r < 8; ++r) { acc0[r] = 0.f; acc1[r] = 0.f; }

    const float* inb = in + row0 * DD;
    #pragma unroll 2
    for (int k = 0; k < DD; k += 4) {
        float4 xv[8];
        #pragma unroll
        for (int r = 0; r < 8; ++r)
            xv[r] = *(const float4*)(inb + r * DD + k);   // lane-uniform -> s_load/L1
        #pragma unroll
        for (int j = 0; j < 4; ++j) {
            float w0 = W[(k + j) * DD + c0];   // coalesced 256B/wave
            float w1 = W[(k + j) * DD + c1];
            #pragma unroll
            for (int r = 0; r < 8; ++r) {
                float x = (j == 0) ? xv[r].x : (j == 1) ? xv[r].y
                        : (j == 2) ? xv[r].z : xv[r].w;
                acc0[r] = fmaf(x, w0, acc0[r]);
                acc1[r] = fmaf(x, w1, acc1[r]);
            }
        }
    }

    float a1v = att[lane];                 // f = c&63 = lane for both slots
    float a2v = att[HIDD + lane];
    #pragma unroll
    for (int r = 0; r < 8; ++r) {
        int row = row0 + r;
        Whb[row * DD + c0] = __float2bfloat16(acc0[r]);
        Whb[row * DD + c1] = __float2bfloat16(acc1[r]);
        float p10 = acc0[r] * a1v, p20 = acc0[r] * a2v;
        float p11 = acc1[r] * a1v, p21 = acc1[r] * a2v;
        #pragma unroll
        for (int off = 32; off; off >>= 1) {
            p10 += __shfl_xor(p10, off);
            p20 += __shfl_xor(p20, off);
            p11 += __shfl_xor(p11, off);
            p21 += __shfl_xor(p21, off);
        }
        if (lane == 0) {
            e1[row * NH + h0] = p10;  e2[row * NH + h0] = p20;
            e1[row * NH + h1] = p11;  e2[row * NH + h1] = p21;
        }
    }
}

// ---------------------------------------------------------------- K2: edge bits (dedup via idempotent OR)
__global__ __launch_bounds__(256) void k2_build(
    const int* __restrict__ edges, unsigned int* __restrict__ adj) {
    int t = blockIdx.x * 256 + threadIdx.x;        // grid == NE exactly
    int r = edges[t * 3 + 0];
    int c = edges[t * 3 + 1];
    atomicOr(&adj[r * WPR + (c >> 5)], 1u << (c & 31));
}

// ---------------------------------------------------------------- K3: per-row GAT (no max-trick: logits small, fp32 exp exact ratio)
__global__ __launch_bounds__(256) void k3_gat(
    const unsigned int* __restrict__ adj, const __hip_bfloat16* __restrict__ Whb,
    const float* __restrict__ e1, const float* __restrict__ e2,
    float* __restrict__ out) {
    int i    = blockIdx.x;
    int t    = threadIdx.x;
    int lane = t & 63, wid = t >> 6;

    __shared__ int   nbr[CAP];
    __shared__ float wgt[CAP][NH];
    __shared__ int   cnt;
    __shared__ float zred[4][NH];

    if (t == 0) cnt = 0;
    __syncthreads();

    float4 e1q = *(const float4*)(e1 + i * NH);
    float  e1v[NH] = {e1q.x, e1q.y, e1q.z, e1q.w};

    // ---- scan bitmask row; softmax numerators inline
    float zl[NH] = {0.f, 0.f, 0.f, 0.f};
    if (t < WPR) {
        unsigned int bits = adj[i * WPR + t];
        while (bits) {
            int bpos = __ffs(bits) - 1;
            bits &= bits - 1;
            int j = t * 32 + bpos;
            int d = atomicAdd(&cnt, 1);
            if (d < CAP) {
                nbr[d] = j;
                float4 ev = *(const float4*)(e2 + j * NH);
                float e2v[NH] = {ev.x, ev.y, ev.z, ev.w};
                #pragma unroll
                for (int h = 0; h < NH; ++h) {
                    float s = e1v[h] + e2v[h];
                    s = (s >= 0.f) ? s : SLOPE * s;      // LeakyReLU
                    float w = __expf(s);
                    wgt[d][h] = w;
                    zl[h] += w;
                }
            }
        }
    }
    // ---- block reduce Z
    #pragma unroll
    for (int off = 32; off; off >>= 1) {
        #pragma unroll
        for (int h = 0; h < NH; ++h) zl[h] += __shfl_xor(zl[h], off);
    }
    if (lane == 0) {
        #pragma unroll
        for (int h = 0; h < NH; ++h) zred[wid][h] = zl[h];
    }
    __syncthreads();               // wgt/nbr/cnt/zred visible

    float Z = zred[0][wid] + zred[1][wid] + zred[2][wid] + zred[3][wid];
    int cn = cnt;
    if (cn > CAP) cn = CAP;

    // ---- gather: thread (h=wid, f=lane); bf16 row segment = 128B coalesced/wave
    float acc = 0.f;
    #pragma unroll 8
    for (int d = 0; d < cn; ++d)
        acc = fmaf(wgt[d][wid],
                   __bfloat162float(Whb[nbr[d] * DD + wid * HIDD + lane]), acc);
    float r = acc / Z;
    out[i * DD + t] = (r > 0.f) ? r : (__expf(r) - 1.f);   // ELU(alpha=1)
}

// ---------------------------------------------------------------- launcher
extern "C" void kernel_launch(void* const* d_in, const int* in_sizes, int n_in,
                              void* d_out, int out_size, void* d_ws, size_t ws_size,
                              hipStream_t stream) {
    const float* inp   = (const float*)d_in[0];
    const int*   edges = (const int*)d_in[1];
    // d_in[2] = num_node (scalar, constant 4096) — unused
    const float* W     = (const float*)d_in[3];
    const float* att   = (const float*)d_in[4];
    float*       out   = (float*)d_out;

    char* ws = (char*)d_ws;
    __hip_bfloat16* Whb = (__hip_bfloat16*)(ws);                   // 2 MB
    float*        e1  = (float*)(ws + (2u << 20));                 // 64 KB
    float*        e2  = (float*)(ws + (2u << 20) + (64u << 10));   // 64 KB
    unsigned int* adj = (unsigned int*)(ws + (2u << 20) + (128u << 10)); // 2 MB

    k1_gemm_e12_zero<<<NN / 16, 256, 0, stream>>>(inp, W, att, Whb, e1, e2, adj);
    k2_build<<<NE / 256, 256, 0, stream>>>(edges, adj);
    k3_gat<<<NN, 256, 0, stream>>>(adj, Whb, e1, e2, out);
}

// Round 8
// 42.418 us; speedup vs baseline: 1.5056x; 1.5056x over previous
//
#include <hip/hip_runtime.h>

#define NN    4096      // nodes
#define DD    256       // feature dim (= H*HID)
#define NH    4         // heads
#define HIDD  64        // per-head hidden
#define NE    131072    // edges
#define WPR   (NN/32)   // 128 u32 words per adjacency bitmask row
#define SLOPE 0.2f
#define CAP   128       // max degree; Binom(131072,1/4096) max over 4096 rows ~56 incl self

typedef __attribute__((ext_vector_type(8))) short short8;   // 8 bf16 in 4 VGPRs
typedef __attribute__((ext_vector_type(4))) float f32x4;

__device__ __forceinline__ unsigned short f2bf(float x) {   // RNE, matches HW cvt
    unsigned u = __float_as_uint(x);
    u += 0x7fffu + ((u >> 16) & 1u);
    return (unsigned short)(u >> 16);
}
__device__ __forceinline__ float bf2f(unsigned short v) {
    return __uint_as_float((unsigned)v << 16);
}

// ---------------------------------------------------------------- K1: MFMA GEMM + adj-zero/self-loops + fused e1/e2
// 1024 blocks x 256 thr (4/CU -> 16 waves/CU; R7 lesson: 1 wave/SIMD = no
// latency hiding). Block b: rows [16(b>>2),+16) x head (b&3); wave wv = one
// 16x16 MFMA tile at cols head*64+16wv, K=256 = 8x mfma_f32_16x16x32_bf16.
// A frag: row=lane&15, k=8*(lane>>4)+j (contiguous 8). B frag: col=lane&15,
// same k. C/D: col=lane&15, row=(lane>>4)*4+reg (m89-verified).
// Since block == one head, e1/e2 dots reduce in-epilogue (16-lane shfl + LDS).
__global__ __launch_bounds__(256) void k1_mfma_gemm(
    const float* __restrict__ in, const float* __restrict__ W,
    const float* __restrict__ att, unsigned short* __restrict__ Whb,
    float* __restrict__ e1, float* __restrict__ e2,
    unsigned int* __restrict__ adj) {
    int b = blockIdx.x;
    int t = threadIdx.x;
    int lane = t & 63, wv = t >> 6;
    int rt = b >> 2, head = b & 3;
    int row0 = rt * 16;
    int col0 = head * 64 + wv * 16;

    // ---- adj zero + self bits: head-0 block owns rows [16rt,16rt+16) slice
    // (512 uint4). Self bit composed into the zeroing store -> no ordering
    // hazard. Visible to k2/k3 by stream order.
    if (head == 0) {
        uint4* adj4 = (uint4*)adj;
        #pragma unroll
        for (int q = 0; q < 2; ++q) {
            int g = rt * 512 + q * 256 + t;     // global uint4 index; 32 per row
            int r = g >> 5;                      // the row this uint4 belongs to
            int sw = r * 128 + (r >> 5);         // word holding row r's self bit
            uint4 z{0u, 0u, 0u, 0u};
            if ((sw >> 2) == g) ((unsigned*)&z)[sw & 3] = 1u << (r & 31);
            adj4[g] = z;
        }
    }

    // ---- MFMA GEMM
    const float* Arow = in + (row0 + (lane & 15)) * DD;
    const float* Bcol = W + col0 + (lane & 15);
    int kb = (lane >> 4) * 8;
    f32x4 acc = {0.f, 0.f, 0.f, 0.f};
    #pragma unroll
    for (int s = 0; s < 8; ++s) {
        int k = s * 32 + kb;
        float4 x0 = *(const float4*)(Arow + k);
        float4 x1 = *(const float4*)(Arow + k + 4);
        short8 af, bfr;
        af[0] = (short)f2bf(x0.x); af[1] = (short)f2bf(x0.y);
        af[2] = (short)f2bf(x0.z); af[3] = (short)f2bf(x0.w);
        af[4] = (short)f2bf(x1.x); af[5] = (short)f2bf(x1.y);
        af[6] = (short)f2bf(x1.z); af[7] = (short)f2bf(x1.w);
        #pragma unroll
        for (int j = 0; j < 8; ++j) bfr[j] = (short)f2bf(Bcol[(k + j) * DD]);
        acc = __builtin_amdgcn_mfma_f32_16x16x32_bf16(af, bfr, acc, 0, 0, 0);
    }

    // ---- store C (bf16) + e1/e2 epilogue
    int rg = lane >> 4, cl = lane & 15;
    int crow = row0 + rg * 4;
    int ccol = col0 + cl;
    float a1w = att[wv * 16 + cl];           // f = col within head
    float a2w = att[HIDD + wv * 16 + cl];
    float p1[4], p2[4];
    #pragma unroll
    for (int r = 0; r < 4; ++r) {
        Whb[(crow + r) * DD + ccol] = f2bf(acc[r]);
        p1[r] = acc[r] * a1w;
        p2[r] = acc[r] * a2w;
    }
    #pragma unroll
    for (int off = 1; off < 16; off <<= 1) {   // reduce over the 16 cols
        #pragma unroll
        for (int r = 0; r < 4; ++r) {
            p1[r] += __shfl_xor(p1[r], off);
            p2[r] += __shfl_xor(p2[r], off);
        }
    }
    __shared__ float s1[4][16], s2[4][16];     // [wave][row-in-tile]
    if (cl == 0) {
        #pragma unroll
        for (int r = 0; r < 4; ++r) {
            s1[wv][rg * 4 + r] = p1[r];
            s2[wv][rg * 4 + r] = p2[r];
        }
    }
    __syncthreads();
    if (t < 16) {
        float v1 = s1[0][t] + s1[1][t] + s1[2][t] + s1[3][t];
        float v2 = s2[0][t] + s2[1][t] + s2[2][t] + s2[3][t];
        e1[(row0 + t) * NH + head] = v1;
        e2[(row0 + t) * NH + head] = v2;
    }
}

// ---------------------------------------------------------------- K2: edge bits (dedup via idempotent OR)
__global__ __launch_bounds__(256) void k2_build(
    const int* __restrict__ edges, unsigned int* __restrict__ adj) {
    int t = blockIdx.x * 256 + threadIdx.x;        // grid == NE exactly
    int r = edges[t * 3 + 0];
    int c = edges[t * 3 + 1];
    atomicOr(&adj[r * WPR + (c >> 5)], 1u << (c & 31));
}

// ---------------------------------------------------------------- K3: per-row GAT (no max-trick: logits small, fp32 exp exact ratio)
__global__ __launch_bounds__(256) void k3_gat(
    const unsigned int* __restrict__ adj, const unsigned short* __restrict__ Whb,
    const float* __restrict__ e1, const float* __restrict__ e2,
    float* __restrict__ out) {
    int i    = blockIdx.x;
    int t    = threadIdx.x;
    int lane = t & 63, wid = t >> 6;

    __shared__ int   nbr[CAP];
    __shared__ float wgt[CAP][NH];
    __shared__ int   cnt;
    __shared__ float zred[4][NH];

    if (t == 0) cnt = 0;
    __syncthreads();

    float4 e1q = *(const float4*)(e1 + i * NH);
    float  e1v[NH] = {e1q.x, e1q.y, e1q.z, e1q.w};

    // ---- scan bitmask row; softmax numerators inline
    float zl[NH] = {0.f, 0.f, 0.f, 0.f};
    if (t < WPR) {
        unsigned int bits = adj[i * WPR + t];
        while (bits) {
            int bpos = __ffs(bits) - 1;
            bits &= bits - 1;
            int j = t * 32 + bpos;
            int d = atomicAdd(&cnt, 1);
            if (d < CAP) {
                nbr[d] = j;
                float4 ev = *(const float4*)(e2 + j * NH);
                float e2v[NH] = {ev.x, ev.y, ev.z, ev.w};
                #pragma unroll
                for (int h = 0; h < NH; ++h) {
                    float s = e1v[h] + e2v[h];
                    s = (s >= 0.f) ? s : SLOPE * s;      // LeakyReLU
                    float w = __expf(s);
                    wgt[d][h] = w;
                    zl[h] += w;
                }
            }
        }
    }
    // ---- block reduce Z
    #pragma unroll
    for (int off = 32; off; off >>= 1) {
        #pragma unroll
        for (int h = 0; h < NH; ++h) zl[h] += __shfl_xor(zl[h], off);
    }
    if (lane == 0) {
        #pragma unroll
        for (int h = 0; h < NH; ++h) zred[wid][h] = zl[h];
    }
    __syncthreads();               // wgt/nbr/cnt/zred visible

    float Z = zred[0][wid] + zred[1][wid] + zred[2][wid] + zred[3][wid];
    int cn = cnt;
    if (cn > CAP) cn = CAP;

    // ---- gather: thread (h=wid, f=lane); bf16 row segment = 128B coalesced/wave
    float acc = 0.f;
    #pragma unroll 8
    for (int d = 0; d < cn; ++d)
        acc = fmaf(wgt[d][wid],
                   bf2f(Whb[nbr[d] * DD + wid * HIDD + lane]), acc);
    float r = acc / Z;
    out[i * DD + t] = (r > 0.f) ? r : (__expf(r) - 1.f);   // ELU(alpha=1)
}

// ---------------------------------------------------------------- launcher
extern "C" void kernel_launch(void* const* d_in, const int* in_sizes, int n_in,
                              void* d_out, int out_size, void* d_ws, size_t ws_size,
                              hipStream_t stream) {
    const float* inp   = (const float*)d_in[0];
    const int*   edges = (const int*)d_in[1];
    // d_in[2] = num_node (scalar, constant 4096) — unused
    const float* W     = (const float*)d_in[3];
    const float* att   = (const float*)d_in[4];
    float*       out   = (float*)d_out;

    char* ws = (char*)d_ws;
    unsigned short* Whb = (unsigned short*)(ws);                   // 2 MB
    float*        e1  = (float*)(ws + (2u << 20));                 // 64 KB
    float*        e2  = (float*)(ws + (2u << 20) + (64u << 10));   // 64 KB
    unsigned int* adj = (unsigned int*)(ws + (2u << 20) + (128u << 10)); // 2 MB

    k1_mfma_gemm<<<NN / 16 * NH, 256, 0, stream>>>(inp, W, att, Whb, e1, e2, adj);
    k2_build<<<NE / 256, 256, 0, stream>>>(edges, adj);
    k3_gat<<<NN, 256, 0, stream>>>(adj, Whb, e1, e2, out);
}